// Round 5
// baseline (1805.347 us; speedup 1.0000x reference)
//
#include <hip/hip_runtime.h>
#include <hip/hip_bf16.h>
#include <stdint.h>

// SubLSTM: T=512, B=64, I=1024, H=1024, G=4096
// Persistent cooperative kernel; barrier-free h exchange, round-5 scheme:
//   TAG-FREE POISON EXCHANGE. h stored as plain packed bf16 (4 per 8B word)
//   in a 4-deep slot rotation. A word is valid iff neither aligned 8B half
//   == 0xFFFFFFFFFFFFFFFF (bf16 0xFFFF = -NaN, unreachable from f2bf of
//   finite h in (-1,1); 8B stores are single-copy atomic).
//   Slot protocol at step t: read slot t&3; publish h_{t+1} -> slot (t+1)&3;
//   poison own region of slot (t+3)&3. Safety: detecting all of h_t implies
//   all blocks finished reading h_{t-1}, so slot (t+3)&3 is dead; poison is
//   made visible before h_{t+1} via s_waitcnt vmcnt(0) before the publish
//   store, and consumers poll that slot >= 2 published generations later.
//   vs round-4: poll bytes AND requests halved (no tags), publish stores
//   halved, poll compare VALU halved.
// 256 blocks = 4 batch-groups(16) x 64 unit-groups(16), 512 thr = 8 waves:
//   wave = (gate gt) x (K-half kh); W_cat fragments persistent in registers.

#define T_STEPS 512
#define NBLK 256

typedef short bf16x8 __attribute__((ext_vector_type(8)));
typedef float f32x4 __attribute__((ext_vector_type(4)));
typedef unsigned int u32x4 __attribute__((ext_vector_type(4)));

// ---- ws layout (bytes) ----
#define WS_XBF    0
#define WS_WCAT   67108864
#define WS_HBUF   83886080          // 4 slots x 64 rows x 2048 B = 512 KB
#define WS_NEEDED (83886080 + 524288 + 256)

// ---- LDS layout (bytes) ----
#define LDS_X0   0          // x tiles, 2 x 32KB double buffer, swizzled
#define LDS_H    65536      // h tile, 32KB, swizzled
#define LDS_G    98304      // gate partials, 8KB
#define LDS_SIZE 106496

__device__ __forceinline__ ushort f2bf(float f) {
  uint32_t u = __float_as_uint(f);
  uint32_t r = (u + 0x7fffu + ((u >> 16) & 1u)) >> 16;
  return (ushort)r;
}

__device__ __forceinline__ float sigmoid_f(float x) {
  float e = __builtin_amdgcn_exp2f(-1.44269504f * x);
  return __builtin_amdgcn_rcpf(1.0f + e);
}

// 16B load bypassing L1+L2 (reads the coherence point / MALL).
__device__ __forceinline__ u32x4 poll_load16(const void* p) {
  u32x4 v;
  asm volatile("global_load_dwordx4 %0, %1, off sc0 sc1"
               : "=v"(v) : "v"(p));
  return v;
}
#define POLL_FENCE() do {                            \
    asm volatile("s_waitcnt vmcnt(0)" ::: "memory"); \
    __builtin_amdgcn_sched_barrier(0);               \
  } while (0)

__global__ void cvt_bf16_kernel(const float* __restrict__ src,
                                ushort* __restrict__ dst, int n4) {
  int i = blockIdx.x * 256 + threadIdx.x;
  if (i >= n4) return;
  float4 v = ((const float4*)src)[i];
  ushort4 o;
  o.x = f2bf(v.x); o.y = f2bf(v.y); o.z = f2bf(v.z); o.w = f2bf(v.w);
  ((ushort4*)dst)[i] = o;
}

// W_cat[g][0:1024] = W_in[g][:], W_cat[g][1024:2048] = W_rec[g][:]
__global__ void build_wcat_kernel(const float* __restrict__ w_in,
                                  const float* __restrict__ w_rec,
                                  ushort* __restrict__ wc) {
  int i = blockIdx.x * 256 + threadIdx.x;
  if (i >= (4096 * 2048) / 4) return;
  int col4 = i & 511;
  int g = i >> 9;
  const float* src = (col4 < 256) ? (w_in + (size_t)g * 1024 + col4 * 4)
                                  : (w_rec + (size_t)g * 1024 + (col4 - 256) * 4);
  float4 v = *(const float4*)src;
  ushort4 o;
  o.x = f2bf(v.x); o.y = f2bf(v.y); o.z = f2bf(v.z); o.w = f2bf(v.w);
  ((ushort4*)wc)[i] = o;
}

// slot0 <- h0 (packed bf16); slots 1..3 <- poison (all-ones).
__global__ void init_hbuf_kernel(const float* __restrict__ h0,
                                 unsigned long long* __restrict__ hb) {
  int i = blockIdx.x * 256 + threadIdx.x;  // 0..65535 over 8B words
  if (i >= 65536) return;
  if (i < 16384) {
    int row = i >> 8, w = i & 255;          // 256 words per 1024-unit row
    const float* s = h0 + (size_t)row * 1024 + w * 4;
    unsigned long long v = 0;
    v |= (unsigned long long)f2bf(s[0]);
    v |= (unsigned long long)f2bf(s[1]) << 16;
    v |= (unsigned long long)f2bf(s[2]) << 32;
    v |= (unsigned long long)f2bf(s[3]) << 48;
    hb[i] = v;
  } else {
    hb[i] = ~0ull;
  }
}

__launch_bounds__(512, 2)
__global__ void sublstm_main(const ushort* __restrict__ xb,
                             const ushort* __restrict__ wc,
                             unsigned long long* __restrict__ hb,
                             const float* __restrict__ c0,
                             const float* __restrict__ bias,
                             float* __restrict__ out) {
  extern __shared__ unsigned char smem[];
  float* gsm = (float*)(smem + LDS_G);

  const int tid  = threadIdx.x;
  const int lane = tid & 63;
  const int wid  = tid >> 6;
  const int gt   = wid >> 1;   // gate: 0=in 1=out 2=z 3=f
  const int kh   = wid & 1;    // K-half: 0 = x, 1 = h
  const int bid  = blockIdx.x;
  const int b0   = (bid & 3) * 16;
  const int j0   = (bid >> 2) * 16;

  // ---- persistent W_cat B-fragments ----
  bf16x8 bfrag[32];
  {
    const int row_g = gt * 1024 + j0 + (lane & 15);
    const ushort* wrow = wc + (size_t)row_g * 2048 + kh * 1024 + ((lane >> 4) * 8);
#pragma unroll
    for (int ks = 0; ks < 32; ++ks)
      bfrag[ks] = *(const bf16x8*)(wrow + ks * 32);
  }

  // ---- cell state + bias (threads 0..255: (batch bb, unit uu)) ----
  const int bb = tid >> 4, uu = tid & 15;
  float c_reg = 0.f;
  float bias_r0 = 0.f, bias_r1 = 0.f, bias_r2 = 0.f, bias_r3 = 0.f;
  if (tid < 256) {
    c_reg = c0[(size_t)(b0 + bb) * 1024 + j0 + uu];
    bias_r0 = bias[0 * 1024 + j0 + uu];
    bias_r1 = bias[1 * 1024 + j0 + uu];
    bias_r2 = bias[2 * 1024 + j0 + uu];
    bias_r3 = bias[3 * 1024 + j0 + uu];
  }

  // ---- fixed addressing ----
  const int prow = tid >> 5;                  // h-poll row 0..15
  const int pc   = tid & 31;                  // h-poll chunk-lane 0..31
  const int arow = lane & 15;
  const int aoff = arow * 2048 + ((lane >> 4) * 16);
  const int aswz = (arow & 7) << 4;
  const int pswz = (prow & 7) << 4;
  // poll: row (b0+prow), 16B chunk pc + i*32  (byte col = pc*16 + i*512)
  const size_t pollbyte = (size_t)(b0 + prow) * 2048 + pc * 16;
  // publish/poison word index within a slot (uu%4==0 lanes): 8B words
  const int pubw = ((b0 + bb) * 2048 + (j0 + uu) * 2) >> 3;

  // ---- prologue: stage x_0 into buffer 0 ----
  {
    const ushort* xrow = xb + (size_t)b0 * 1024;
#pragma unroll
    for (int j = 0; j < 4; ++j) {
      int L = (tid + j * 512) * 16;            // 0..32767
      int row = L >> 11;
      int colb = L & 2047;
      uint4 v = *(const uint4*)(xrow + (size_t)row * 1024 + (colb >> 1));
      *(uint4*)(smem + (L ^ ((row & 7) << 4))) = v;
    }
  }

  for (int t = 0; t < T_STEPS; ++t) {
    // ---- poll h_t (slot t&3): 4 x dwordx4 data-only, poison-validated ----
    {
      const unsigned char* pb =
          (const unsigned char*)hb + ((size_t)(t & 3) << 17) + pollbyte;
      u32x4 vv[4];
#pragma unroll
      for (int i = 0; i < 4; ++i) vv[i] = poll_load16(pb + i * 512);
      POLL_FENCE();
      for (;;) {
        unsigned np = 0;
#pragma unroll
        for (int i = 0; i < 4; ++i) {
          if (((vv[i].x & vv[i].y) == 0xFFFFFFFFu) ||
              ((vv[i].z & vv[i].w) == 0xFFFFFFFFu))
            np |= (1u << i);
        }
        if (!np) break;
        __builtin_amdgcn_s_sleep(1);
#pragma unroll
        for (int i = 0; i < 4; ++i)
          if (np & (1u << i)) vv[i] = poll_load16(pb + i * 512);
        POLL_FENCE();
      }
      // stage 8 bf16 per chunk -> swizzled LDS h tile
#pragma unroll
      for (int i = 0; i < 4; ++i)
        *(u32x4*)(smem + LDS_H + ((prow * 2048 + pc * 16 + i * 512) ^ pswz)) = vv[i];
    }

    // ---- poison own region of slot (t+3)&3 (dead by the detect proof);
    //      made visible before the h_{t+1} publish by the vmcnt(0) below ----
    if (tid < 256 && (uu & 3) == 0) {
      unsigned long long* pz = hb + ((size_t)((t + 3) & 3) << 14) + pubw;
      __hip_atomic_store(pz, ~0ull, __ATOMIC_RELAXED, __HIP_MEMORY_SCOPE_AGENT);
    }
    __syncthreads();   // syncA: h staged (x staged last step / prologue)

    // ---- MFMA over this wave's K-half, 4 independent acc chains ----
    const int abase = (kh ? LDS_H : LDS_X0 + ((t & 1) << 15)) + aoff;
    f32x4 acc0 = {0.f, 0.f, 0.f, 0.f}, acc1 = {0.f, 0.f, 0.f, 0.f};
    f32x4 acc2 = {0.f, 0.f, 0.f, 0.f}, acc3 = {0.f, 0.f, 0.f, 0.f};
#pragma unroll
    for (int ks = 0; ks < 32; ks += 4) {
      bf16x8 a0 = *(const bf16x8*)(smem + ((abase + (ks + 0) * 64) ^ aswz));
      bf16x8 a1 = *(const bf16x8*)(smem + ((abase + (ks + 1) * 64) ^ aswz));
      bf16x8 a2 = *(const bf16x8*)(smem + ((abase + (ks + 2) * 64) ^ aswz));
      bf16x8 a3 = *(const bf16x8*)(smem + ((abase + (ks + 3) * 64) ^ aswz));
      acc0 = __builtin_amdgcn_mfma_f32_16x16x32_bf16(a0, bfrag[ks + 0], acc0, 0, 0, 0);
      acc1 = __builtin_amdgcn_mfma_f32_16x16x32_bf16(a1, bfrag[ks + 1], acc1, 0, 0, 0);
      acc2 = __builtin_amdgcn_mfma_f32_16x16x32_bf16(a2, bfrag[ks + 2], acc2, 0, 0, 0);
      acc3 = __builtin_amdgcn_mfma_f32_16x16x32_bf16(a3, bfrag[ks + 3], acc3, 0, 0, 0);
    }

    // ---- gate partials -> LDS ----
#pragma unroll
    for (int r = 0; r < 4; ++r)
      gsm[wid * 256 + ((lane >> 4) * 4 + r) * 16 + (lane & 15)] =
          (acc0[r] + acc1[r]) + (acc2[r] + acc3[r]);
    __syncthreads();   // syncB: MFMA LDS reads + gate writes done

    // ---- cell update; publish h FIRST, then out (threads 0..255) ----
    if (tid < 256) {
      float p_in  = gsm[0 * 256 + tid] + gsm[1 * 256 + tid] + bias_r0;
      float p_out = gsm[2 * 256 + tid] + gsm[3 * 256 + tid] + bias_r1;
      float p_z   = gsm[4 * 256 + tid] + gsm[5 * 256 + tid] + bias_r2;
      float p_f   = gsm[6 * 256 + tid] + gsm[7 * 256 + tid] + bias_r3;
      float g_in  = sigmoid_f(p_in);
      float g_out = sigmoid_f(p_out);
      float g_z   = sigmoid_f(p_z);
      float g_f   = sigmoid_f(p_f);
      c_reg = c_reg * g_f + g_z - g_in;
      float h_new = sigmoid_f(c_reg) - g_out;

      // pack 4 units per 8B word: uu, uu+1, uu+2, uu+3 (little-endian)
      unsigned hbits = (unsigned)f2bf(h_new);
      unsigned p1 = (unsigned)__shfl_xor((int)hbits, 1);
      unsigned w0 = ((uu & 1) == 0) ? (hbits | (p1 << 16)) : 0u;
      unsigned w2 = (unsigned)__shfl_xor((int)w0, 2);
      if ((uu & 3) == 0) {
        unsigned long long v =
            (unsigned long long)w0 | ((unsigned long long)w2 << 32);
        // ensure the poison stores above are visible BEFORE this publish
        asm volatile("s_waitcnt vmcnt(0)" ::: "memory");
        unsigned long long* pw = hb + ((size_t)((t + 1) & 3) << 14) + pubw;
        __hip_atomic_store(pw, v, __ATOMIC_RELAXED, __HIP_MEMORY_SCOPE_AGENT);
      }
      size_t oidx = (size_t)(b0 + bb) * 1024 + j0 + uu;
      out[(size_t)t * 65536 + oidx] = h_new;
      if (t == T_STEPS - 1) {
        out[(size_t)T_STEPS * 65536 + oidx] = h_new;           // hT
        out[(size_t)T_STEPS * 65536 + 65536 + oidx] = c_reg;   // cT
      }
    }

    // ---- stage x_{t+1} (off critical path; protected by syncA(t+1)) ----
    if (t + 1 < T_STEPS) {
      const ushort* xrow = xb + ((size_t)(t + 1) * 64 + b0) * 1024;
      const int xo = ((t + 1) & 1) << 15;
#pragma unroll
      for (int j = 0; j < 4; ++j) {
        int L = (tid + j * 512) * 16;
        int row = L >> 11;
        int colb = L & 2047;
        uint4 v = *(const uint4*)(xrow + (size_t)row * 1024 + (colb >> 1));
        *(uint4*)(smem + xo + (L ^ ((row & 7) << 4))) = v;
      }
    }
    // no loop-end barrier: staging writes for t+1 only touch regions whose
    // step-t readers finished before syncB(t); gsm reads of step t complete
    // before this thread reaches syncA(t+1).
  }
}

extern "C" void kernel_launch(void* const* d_in, const int* in_sizes, int n_in,
                              void* d_out, int out_size, void* d_ws, size_t ws_size,
                              hipStream_t stream) {
  const float* x     = (const float*)d_in[0];
  const float* h0    = (const float*)d_in[1];
  const float* c0    = (const float*)d_in[2];
  const float* w_in  = (const float*)d_in[3];
  const float* biasp = (const float*)d_in[4];
  const float* w_rec = (const float*)d_in[5];
  float* outp = (float*)d_out;

  if (ws_size < (size_t)WS_NEEDED) return;

  uint8_t* ws = (uint8_t*)d_ws;
  ushort* xbp = (ushort*)(ws + WS_XBF);
  ushort* wcp = (ushort*)(ws + WS_WCAT);
  unsigned long long* hbp = (unsigned long long*)(ws + WS_HBUF);

  hipFuncSetAttribute(reinterpret_cast<const void*>(sublstm_main),
                      hipFuncAttributeMaxDynamicSharedMemorySize, LDS_SIZE);

  cvt_bf16_kernel<<<32768, 256, 0, stream>>>(x, xbp, 8388608);
  build_wcat_kernel<<<8192, 256, 0, stream>>>(w_in, w_rec, wcp);
  init_hbuf_kernel<<<256, 256, 0, stream>>>(h0, hbp);

  void* kargs[] = { (void*)&xbp, (void*)&wcp, (void*)&hbp,
                    (void*)&c0,  (void*)&biasp, (void*)&outp };
  hipLaunchCooperativeKernel((void*)sublstm_main, dim3(NBLK), dim3(512),
                             kargs, LDS_SIZE, stream);
}